// Round 1
// baseline (1090.519 us; speedup 1.0000x reference)
//
#include <hip/hip_runtime.h>
#include <hip/hip_bf16.h>
#include <math.h>

// Problem constants (from reference)
#define BB 64      // batch
#define SS 256     // click seq len
#define KK 10      // unclick per click
#define DD 64      // emb dim
#define H1N 80     // attention MLP hidden 1
#define H2N 40     // attention MLP hidden 2
#define FF 192     // 3*D
#define FH1 200
#define FH2 80
#define BIG_NEG_F (-4294967295.0f)

__device__ __forceinline__ float sigmoidf_(float x) {
    return 1.0f / (1.0f + expf(-x));
}

// ---------------------------------------------------------------------------
// Kernel 1: per (b,s) DIN over K unclick facts -> un_att[B,S,D], click[B,S,D],
// coef[B,S] = 1 + dot(un_att,click)/(||click||^2+1e-12)
// ---------------------------------------------------------------------------
__global__ __launch_bounds__(128) void k_unatt(
    const int* __restrict__ click_his, const int* __restrict__ unclick_his,
    const float* __restrict__ click_mask, const float* __restrict__ unclick_mask,
    const float* __restrict__ emb,
    const float* __restrict__ W1, const float* __restrict__ b1,
    const float* __restrict__ W2, const float* __restrict__ b2,
    const float* __restrict__ W3, const float* __restrict__ b3,
    float* __restrict__ click_out, float* __restrict__ unatt_out,
    float* __restrict__ coef_out)
{
    const int bs = blockIdx.x;           // b*S + s
    const int b  = bs >> 8;
    const int s  = bs & (SS - 1);
    const int t  = threadIdx.x;

    __shared__ float q[DD];
    __shared__ float facts[KK][DD];
    __shared__ float h1[H1N];
    __shared__ float h2[H2N];
    __shared__ float sc[KK];

    if (t < DD) {
        int idx = click_his[bs];
        float v = emb[idx * DD + t] * click_mask[bs];
        q[t] = v;
        click_out[bs * DD + t] = v;
    }
    for (int e = t; e < KK * DD; e += 128) {
        int k = e >> 6, d = e & 63;
        int off = b * (KK * SS) + s * KK + k;
        facts[k][d] = emb[unclick_his[off] * DD + d] * unclick_mask[off];
    }
    __syncthreads();

    for (int k = 0; k < KK; ++k) {
        if (t < H1N) {
            float acc = b1[t];
            #pragma unroll 4
            for (int i = 0; i < DD; ++i) {
                float qi = q[i], fi = facts[k][i];
                acc += qi        * W1[(i       ) * H1N + t];
                acc += fi        * W1[(DD + i  ) * H1N + t];
                acc += (qi - fi) * W1[(2*DD + i) * H1N + t];
                acc += (qi * fi) * W1[(3*DD + i) * H1N + t];
            }
            h1[t] = sigmoidf_(acc);
        }
        __syncthreads();
        if (t < H2N) {
            float acc = b2[t];
            #pragma unroll 4
            for (int i = 0; i < H1N; ++i) acc += h1[i] * W2[i * H2N + t];
            h2[t] = sigmoidf_(acc);
        }
        __syncthreads();
        if (t == 0) {
            float acc = b3[0];
            for (int i = 0; i < H2N; ++i) acc += h2[i] * W3[i];
            float m = unclick_mask[b * (KK * SS) + s * KK + k];
            sc[k] = (m == 1.0f) ? acc : BIG_NEG_F;
        }
        __syncthreads();
    }

    if (t == 0) {
        float mx = sc[0];
        for (int k = 1; k < KK; ++k) mx = fmaxf(mx, sc[k]);
        float sum = 0.0f;
        for (int k = 0; k < KK; ++k) { float e = expf(sc[k] - mx); sc[k] = e; sum += e; }
        float inv = 1.0f / sum;
        for (int k = 0; k < KK; ++k) sc[k] *= inv;
    }
    __syncthreads();

    if (t < DD) {
        float acc = 0.0f;
        for (int k = 0; k < KK; ++k) acc += sc[k] * facts[k][t];
        unatt_out[bs * DD + t] = acc;
        float qv = q[t];
        float dp = acc * qv;
        float nq = qv * qv;
        #pragma unroll
        for (int o = 32; o > 0; o >>= 1) {
            dp += __shfl_down(dp, o, 64);
            nq += __shfl_down(nq, o, 64);
        }
        if (t == 0) coef_out[bs] = 1.0f + dp / (nq + 1e-12f);
    }
}

// ---------------------------------------------------------------------------
// Kernel 2: attention scores for att1 (facts=click*coef, cW*) and att2
// (facts=un_att, uW*). One block per (s, b, type). scores[type][B][S]
// ---------------------------------------------------------------------------
__global__ __launch_bounds__(128) void k_scores(
    const int* __restrict__ mid, const float* __restrict__ emb,
    const float* __restrict__ click, const float* __restrict__ unatt,
    const float* __restrict__ coef, const float* __restrict__ click_mask,
    const float* __restrict__ cW1, const float* __restrict__ cb1,
    const float* __restrict__ cW2, const float* __restrict__ cb2,
    const float* __restrict__ cW3, const float* __restrict__ cb3,
    const float* __restrict__ uW1, const float* __restrict__ ub1,
    const float* __restrict__ uW2, const float* __restrict__ ub2,
    const float* __restrict__ uW3, const float* __restrict__ ub3,
    float* __restrict__ scores)
{
    const int s  = blockIdx.x;
    const int b  = blockIdx.y;
    const int ty = blockIdx.z;
    const int t  = threadIdx.x;
    const int bs = b * SS + s;

    const float* W1 = ty ? uW1 : cW1; const float* b1 = ty ? ub1 : cb1;
    const float* W2 = ty ? uW2 : cW2; const float* b2 = ty ? ub2 : cb2;
    const float* W3 = ty ? uW3 : cW3; const float* b3 = ty ? ub3 : cb3;

    __shared__ float q[DD];
    __shared__ float f[DD];
    __shared__ float h1[H1N];
    __shared__ float h2[H2N];

    if (t < DD) {
        q[t] = emb[mid[b] * DD + t];
        f[t] = ty ? unatt[bs * DD + t] : click[bs * DD + t] * coef[bs];
    }
    __syncthreads();

    if (t < H1N) {
        float acc = b1[t];
        #pragma unroll 4
        for (int i = 0; i < DD; ++i) {
            float qi = q[i], fi = f[i];
            acc += qi        * W1[(i       ) * H1N + t];
            acc += fi        * W1[(DD + i  ) * H1N + t];
            acc += (qi - fi) * W1[(2*DD + i) * H1N + t];
            acc += (qi * fi) * W1[(3*DD + i) * H1N + t];
        }
        h1[t] = sigmoidf_(acc);
    }
    __syncthreads();
    if (t < H2N) {
        float acc = b2[t];
        #pragma unroll 4
        for (int i = 0; i < H1N; ++i) acc += h1[i] * W2[i * H2N + t];
        h2[t] = sigmoidf_(acc);
    }
    __syncthreads();
    if (t == 0) {
        float acc = b3[0];
        for (int i = 0; i < H2N; ++i) acc += h2[i] * W3[i];
        float m = click_mask[bs];
        scores[ty * (BB * SS) + bs] = (m == 1.0f) ? acc : BIG_NEG_F;
    }
}

// ---------------------------------------------------------------------------
// Kernel 3: per (b, type) softmax over S=256 scores + weighted fact sum
// ---------------------------------------------------------------------------
__global__ __launch_bounds__(256) void k_attend(
    const float* __restrict__ click, const float* __restrict__ unatt,
    const float* __restrict__ coef, const float* __restrict__ scores,
    float* __restrict__ att1, float* __restrict__ att2)
{
    const int b  = blockIdx.x;
    const int ty = blockIdx.y;
    const int t  = threadIdx.x;

    __shared__ float a[SS];

    a[t] = scores[ty * (BB * SS) + b * SS + t];
    __syncthreads();
    if (t == 0) {
        float mx = a[0];
        for (int i = 1; i < SS; ++i) mx = fmaxf(mx, a[i]);
        float sum = 0.0f;
        for (int i = 0; i < SS; ++i) { float e = expf(a[i] - mx); a[i] = e; sum += e; }
        float inv = 1.0f / sum;
        for (int i = 0; i < SS; ++i) a[i] *= inv;
    }
    __syncthreads();

    if (t < DD) {
        float acc = 0.0f;
        for (int s2 = 0; s2 < SS; ++s2) {
            int bs = b * SS + s2;
            float fact = ty ? unatt[bs * DD + t] : click[bs * DD + t] * coef[bs];
            acc += a[s2] * fact;
        }
        if (ty == 0) att1[b * DD + t] = acc;
        else         att2[b * DD + t] = acc;
    }
}

// ---------------------------------------------------------------------------
// Kernel 4: final head — BN + 192->200->80->2 PReLU MLP + softmax(+1e-8)
// ---------------------------------------------------------------------------
__global__ __launch_bounds__(256) void k_final(
    const int* __restrict__ mid, const float* __restrict__ emb,
    const float* __restrict__ att1, const float* __restrict__ att2,
    const float* __restrict__ bn_g, const float* __restrict__ bn_b,
    const float* __restrict__ bn_m, const float* __restrict__ bn_v,
    const float* __restrict__ fW1, const float* __restrict__ fb1, const float* __restrict__ a1,
    const float* __restrict__ fW2, const float* __restrict__ fb2, const float* __restrict__ a2,
    const float* __restrict__ fW3, const float* __restrict__ fb3,
    float* __restrict__ out)
{
    const int b = blockIdx.x;
    const int t = threadIdx.x;

    __shared__ float x[FF];
    __shared__ float h1[FH1];
    __shared__ float h2[FH2];

    if (t < DD) {
        x[t]          = emb[mid[b] * DD + t];
        x[DD + t]     = att1[b * DD + t];
        x[2 * DD + t] = att2[b * DD + t];
    }
    __syncthreads();
    if (t < FF) {
        x[t] = (x[t] - bn_m[t]) * rsqrtf(bn_v[t] + 1e-3f) * bn_g[t] + bn_b[t];
    }
    __syncthreads();
    if (t < FH1) {
        float acc = fb1[t];
        #pragma unroll 4
        for (int i = 0; i < FF; ++i) acc += x[i] * fW1[i * FH1 + t];
        h1[t] = fmaxf(acc, 0.0f) + a1[t] * fminf(acc, 0.0f);
    }
    __syncthreads();
    if (t < FH2) {
        float acc = fb2[t];
        #pragma unroll 4
        for (int i = 0; i < FH1; ++i) acc += h1[i] * fW2[i * FH2 + t];
        h2[t] = fmaxf(acc, 0.0f) + a2[t] * fminf(acc, 0.0f);
    }
    __syncthreads();
    if (t == 0) {
        float l0 = fb3[0], l1 = fb3[1];
        for (int i = 0; i < FH2; ++i) {
            l0 += h2[i] * fW3[i * 2 + 0];
            l1 += h2[i] * fW3[i * 2 + 1];
        }
        float mx = fmaxf(l0, l1);
        float e0 = expf(l0 - mx), e1 = expf(l1 - mx);
        float inv = 1.0f / (e0 + e1);
        out[b * 2 + 0] = e0 * inv + 1e-8f;
        out[b * 2 + 1] = e1 * inv + 1e-8f;
    }
}

// ---------------------------------------------------------------------------
extern "C" void kernel_launch(void* const* d_in, const int* in_sizes, int n_in,
                              void* d_out, int out_size, void* d_ws, size_t ws_size,
                              hipStream_t stream) {
    const int*   mid          = (const int*)d_in[0];
    const int*   click_his    = (const int*)d_in[1];
    const int*   unclick_his  = (const int*)d_in[2];
    const float* click_mask   = (const float*)d_in[3];
    const float* unclick_mask = (const float*)d_in[4];
    const float* emb          = (const float*)d_in[5];
    const float* sW1 = (const float*)d_in[6];  const float* sb1 = (const float*)d_in[7];
    const float* sW2 = (const float*)d_in[8];  const float* sb2 = (const float*)d_in[9];
    const float* sW3 = (const float*)d_in[10]; const float* sb3 = (const float*)d_in[11];
    const float* cW1 = (const float*)d_in[12]; const float* cb1 = (const float*)d_in[13];
    const float* cW2 = (const float*)d_in[14]; const float* cb2 = (const float*)d_in[15];
    const float* cW3 = (const float*)d_in[16]; const float* cb3 = (const float*)d_in[17];
    const float* uW1 = (const float*)d_in[18]; const float* ub1 = (const float*)d_in[19];
    const float* uW2 = (const float*)d_in[20]; const float* ub2 = (const float*)d_in[21];
    const float* uW3 = (const float*)d_in[22]; const float* ub3 = (const float*)d_in[23];
    const float* bn_g = (const float*)d_in[24]; const float* bn_b = (const float*)d_in[25];
    const float* bn_m = (const float*)d_in[26]; const float* bn_v = (const float*)d_in[27];
    const float* fW1 = (const float*)d_in[28]; const float* fb1 = (const float*)d_in[29];
    const float* a1  = (const float*)d_in[30];
    const float* fW2 = (const float*)d_in[31]; const float* fb2 = (const float*)d_in[32];
    const float* a2  = (const float*)d_in[33];
    const float* fW3 = (const float*)d_in[34]; const float* fb3 = (const float*)d_in[35];

    float* out = (float*)d_out;

    // Workspace layout (floats): 8.6 MB total
    float* ws      = (float*)d_ws;
    float* click   = ws;                         // B*S*D = 1048576
    float* unatt   = click + BB * SS * DD;       // B*S*D
    float* coef    = unatt + BB * SS * DD;       // B*S
    float* scores  = coef + BB * SS;             // 2*B*S
    float* att1    = scores + 2 * BB * SS;       // B*D
    float* att2    = att1 + BB * DD;             // B*D

    hipLaunchKernelGGL(k_unatt, dim3(BB * SS), dim3(128), 0, stream,
        click_his, unclick_his, click_mask, unclick_mask, emb,
        sW1, sb1, sW2, sb2, sW3, sb3,
        click, unatt, coef);

    hipLaunchKernelGGL(k_scores, dim3(SS, BB, 2), dim3(128), 0, stream,
        mid, emb, click, unatt, coef, click_mask,
        cW1, cb1, cW2, cb2, cW3, cb3,
        uW1, ub1, uW2, ub2, uW3, ub3,
        scores);

    hipLaunchKernelGGL(k_attend, dim3(BB, 2), dim3(256), 0, stream,
        click, unatt, coef, scores, att1, att2);

    hipLaunchKernelGGL(k_final, dim3(BB), dim3(256), 0, stream,
        mid, emb, att1, att2,
        bn_g, bn_b, bn_m, bn_v,
        fW1, fb1, a1, fW2, fb2, a2, fW3, fb3,
        out);
}

// Round 2
// 287.375 us; speedup vs baseline: 3.7948x; 3.7948x over previous
//
#include <hip/hip_runtime.h>
#include <hip/hip_bf16.h>
#include <math.h>

// Problem constants
#define BB 64      // batch
#define SS 256     // click seq len
#define KK 10      // unclick per click
#define DD 64      // emb dim
#define FF 192     // 3*D
#define FH1 200
#define FH2 80
#define BIG_NEG_F (-4294967295.0f)

// LDS strides (padded: 16B-aligned rows, <=2-way bank aliasing)
#define XSTR 200   // X / W1t row stride in bf16 (192 + 8 pad)
#define H1STR 104  // h1 / W2t row stride in bf16 (96 + 8 pad)
#define H2STR 49   // h2 row stride in fp32

typedef __bf16 bfrag __attribute__((ext_vector_type(8)));
typedef float f32x4 __attribute__((ext_vector_type(4)));

__device__ __forceinline__ float sigm_(float x) { return 1.0f / (1.0f + __expf(-x)); }

// ---------------------------------------------------------------------------
// Prep: fold W1 (256x80) -> W1t[n][k] bf16 [80][200]: k<64: q-coef = W1a+W1c;
// 64..127: f-coef = W1b-W1c; 128..191: (q*f)-coef = W1d. Also W2 (80x40) ->
// W2t[n][k] bf16 [48][104] zero-padded. One block per MLP (s, c, u).
// ---------------------------------------------------------------------------
__global__ __launch_bounds__(256) void k_prep(
    const float* __restrict__ sW1, const float* __restrict__ sW2,
    const float* __restrict__ cW1, const float* __restrict__ cW2,
    const float* __restrict__ uW1, const float* __restrict__ uW2,
    __bf16* __restrict__ W1t, __bf16* __restrict__ W2t)
{
    const int p = blockIdx.x;
    const float* W1 = (p == 0) ? sW1 : (p == 1) ? cW1 : uW1;   // [256][80]
    const float* W2 = (p == 0) ? sW2 : (p == 1) ? cW2 : uW2;   // [80][40]
    __bf16* o1 = W1t + p * 80 * XSTR;
    __bf16* o2 = W2t + p * 48 * H1STR;
    for (int e = threadIdx.x; e < 80 * XSTR; e += 256) {
        const int n = e / XSTR, k = e % XSTR;
        float v = 0.0f;
        if (k < 64)       v = W1[k * 80 + n] + W1[(128 + k) * 80 + n];
        else if (k < 128) { const int kk = k - 64;  v = W1[(64 + kk) * 80 + n] - W1[(128 + kk) * 80 + n]; }
        else if (k < 192) { const int kk = k - 128; v = W1[(192 + kk) * 80 + n]; }
        o1[e] = (__bf16)v;
    }
    for (int e = threadIdx.x; e < 48 * H1STR; e += 256) {
        const int n = e / H1STR, k = e % H1STR;
        o2[e] = (__bf16)((n < 40 && k < 80) ? W2[k * 40 + n] : 0.0f);
    }
}

// ---------------------------------------------------------------------------
// Fused DIN MLP scores: block = 64 rows, 4 waves. Layer1 (K=192,N=80) and
// layer2 (K=96,N=48) via 16x16x32 bf16 MFMA; layer3 dot-40 in VALU.
// mode 0: rows = (bs,k) over unclick facts (M=163840), q=click, f=unclick
// mode 1: rows = bs (M=16384), q=item, f=click*coef
// mode 2: rows = bs (M=16384), q=item, f=un_att
// ---------------------------------------------------------------------------
__global__ __launch_bounds__(256, 2) void k_din(
    const int mode,
    const int* __restrict__ mid,
    const int* __restrict__ click_his,
    const int* __restrict__ unclick_his,
    const float* __restrict__ click_mask,
    const float* __restrict__ unclick_mask,
    const float* __restrict__ emb,
    const float* __restrict__ unatt_in,
    const float* __restrict__ coef,
    const __bf16* __restrict__ W1t,
    const __bf16* __restrict__ W2t,
    const float* __restrict__ b1,
    const float* __restrict__ b2,
    const float* __restrict__ W3,
    const float* __restrict__ b3,
    float* __restrict__ scores_out)
{
    __shared__ __align__(16) __bf16 sW1[80 * XSTR];   // 32000 B; reused as H2 (fp32) later
    __shared__ __align__(16) __bf16 sX [64 * XSTR];   // 25600 B; reused as H1 later
    __shared__ __align__(16) __bf16 sW2[48 * H1STR];  // 9984 B

    const int t = threadIdx.x;

    // ---- stage folded weights (flat 16B copies) ----
    {
        const uint4* s1 = (const uint4*)W1t;  uint4* d1 = (uint4*)sW1;
        for (int e = t; e < 80 * XSTR / 8; e += 256) d1[e] = s1[e];
        const uint4* s2 = (const uint4*)W2t;  uint4* d2 = (uint4*)sW2;
        for (int e = t; e < 48 * H1STR / 8; e += 256) d2[e] = s2[e];
    }

    // ---- build X = [q | f | q*f] bf16, 4 threads per row x 16 cols ----
    {
        const int r  = t >> 2;
        const int c0 = (t & 3) << 4;
        const int m  = blockIdx.x * 64 + r;
        const float* qp; const float* fp;
        float qs = 1.0f, fs = 1.0f;
        if (mode == 0) {
            const int bs = m / 10;
            qp = emb + (size_t)click_his[bs] * DD;   qs = click_mask[bs];
            fp = emb + (size_t)unclick_his[m] * DD;  fs = unclick_mask[m];
        } else {
            const int b = m >> 8;
            qp = emb + (size_t)mid[b] * DD;
            if (mode == 1) { fp = emb + (size_t)click_his[m] * DD; fs = click_mask[m] * coef[m]; }
            else           { fp = unatt_in + (size_t)m * DD; }
        }
        __bf16* xr = sX + r * XSTR;
        #pragma unroll
        for (int i = 0; i < 4; ++i) {
            const int d = c0 + i * 4;
            const float4 qv = *(const float4*)(qp + d);
            const float4 fv = *(const float4*)(fp + d);
            const float qa[4] = {qv.x * qs, qv.y * qs, qv.z * qs, qv.w * qs};
            const float fa[4] = {fv.x * fs, fv.y * fs, fv.z * fs, fv.w * fs};
            #pragma unroll
            for (int j = 0; j < 4; ++j) {
                xr[d + j]       = (__bf16)qa[j];
                xr[64 + d + j]  = (__bf16)fa[j];
                xr[128 + d + j] = (__bf16)(qa[j] * fa[j]);
            }
        }
    }
    __syncthreads();

    const int wave = t >> 6, lane = t & 63;
    const int quad = lane >> 4, l15 = lane & 15;

    // ---- layer 1: [64x192] @ [192x80] ----
    bfrag af[6];
    {
        const __bf16* xrow = sX + (wave * 16 + l15) * XSTR + quad * 8;
        #pragma unroll
        for (int kc = 0; kc < 6; ++kc) af[kc] = *(const bfrag*)(xrow + kc * 32);
    }
    f32x4 acc[5];
    #pragma unroll
    for (int nt = 0; nt < 5; ++nt) acc[nt] = (f32x4){0.f, 0.f, 0.f, 0.f};
    {
        const __bf16* wbase = sW1 + l15 * XSTR + quad * 8;
        #pragma unroll
        for (int nt = 0; nt < 5; ++nt) {
            const __bf16* wp = wbase + nt * 16 * XSTR;
            #pragma unroll
            for (int kc = 0; kc < 6; ++kc)
                acc[nt] = __builtin_amdgcn_mfma_f32_16x16x32_bf16(
                    af[kc], *(const bfrag*)(wp + kc * 32), acc[nt], 0, 0, 0);
        }
    }
    __syncthreads();   // all waves done reading sX/sW1

    // ---- sigmoid -> H1 (aliases sX), zero-pad cols [80,96) ----
    __bf16* sH1 = sX;
    #pragma unroll
    for (int nt = 0; nt < 5; ++nt) {
        const int n = nt * 16 + l15;
        const float bb = b1[n];
        #pragma unroll
        for (int rg = 0; rg < 4; ++rg) {
            const int row = wave * 16 + quad * 4 + rg;
            sH1[row * H1STR + n] = (__bf16)sigm_(acc[nt][rg] + bb);
        }
    }
    for (int e = t; e < 64 * 16; e += 256) {
        const int row = e >> 4, cc = 80 + (e & 15);
        sH1[row * H1STR + cc] = (__bf16)0.0f;
    }
    __syncthreads();

    // ---- layer 2: [64x96] @ [96x48] ----
    bfrag af2[3];
    {
        const __bf16* hrow = sH1 + (wave * 16 + l15) * H1STR + quad * 8;
        #pragma unroll
        for (int kc = 0; kc < 3; ++kc) af2[kc] = *(const bfrag*)(hrow + kc * 32);
    }
    f32x4 acc2[3];
    #pragma unroll
    for (int nt = 0; nt < 3; ++nt) acc2[nt] = (f32x4){0.f, 0.f, 0.f, 0.f};
    {
        const __bf16* wbase = sW2 + l15 * H1STR + quad * 8;
        #pragma unroll
        for (int nt = 0; nt < 3; ++nt) {
            const __bf16* wp = wbase + nt * 16 * H1STR;
            #pragma unroll
            for (int kc = 0; kc < 3; ++kc)
                acc2[nt] = __builtin_amdgcn_mfma_f32_16x16x32_bf16(
                    af2[kc], *(const bfrag*)(wp + kc * 32), acc2[nt], 0, 0, 0);
        }
    }
    // H2 (fp32) aliases sW1 (last read before the H1-write barrier) — safe.
    float* sH2 = (float*)sW1;
    #pragma unroll
    for (int nt = 0; nt < 3; ++nt) {
        const int n = nt * 16 + l15;
        if (n < 40) {
            const float bb = b2[n];
            #pragma unroll
            for (int rg = 0; rg < 4; ++rg) {
                const int row = wave * 16 + quad * 4 + rg;
                sH2[row * H2STR + n] = sigm_(acc2[nt][rg] + bb);
            }
        }
    }
    __syncthreads();

    // ---- layer 3: dot-40 + mask ----
    if (t < 64) {
        float s = b3[0];
        #pragma unroll 8
        for (int i = 0; i < 40; ++i) s += sH2[t * H2STR + i] * W3[i];
        const int m = blockIdx.x * 64 + t;
        const float mk = (mode == 0) ? unclick_mask[m] : click_mask[m];
        scores_out[m] = (mk == 1.0f) ? s : BIG_NEG_F;
    }
}

// ---------------------------------------------------------------------------
// Softmax over K=10 + weighted unclick sum -> un_att[16384][64], coef[16384]
// 4 bs per block (one wave each).
// ---------------------------------------------------------------------------
__global__ __launch_bounds__(256) void k_reduceK(
    const int* __restrict__ click_his, const int* __restrict__ unclick_his,
    const float* __restrict__ click_mask, const float* __restrict__ unclick_mask,
    const float* __restrict__ emb, const float* __restrict__ scores_s,
    float* __restrict__ unatt, float* __restrict__ coef)
{
    const int lane = threadIdx.x & 63;
    const int bs = blockIdx.x * 4 + (threadIdx.x >> 6);
    float sc[KK];
    float mx = -INFINITY;
    #pragma unroll
    for (int k = 0; k < KK; ++k) { sc[k] = scores_s[bs * KK + k]; mx = fmaxf(mx, sc[k]); }
    float sum = 0.0f;
    #pragma unroll
    for (int k = 0; k < KK; ++k) { sc[k] = __expf(sc[k] - mx); sum += sc[k]; }
    const float inv = 1.0f / sum;
    float acc = 0.0f;
    #pragma unroll
    for (int k = 0; k < KK; ++k) {
        const int off = bs * KK + k;
        acc += sc[k] * inv * (emb[(size_t)unclick_his[off] * DD + lane] * unclick_mask[off]);
    }
    unatt[bs * DD + lane] = acc;
    const float qv = emb[(size_t)click_his[bs] * DD + lane] * click_mask[bs];
    float dp = acc * qv, nq = qv * qv;
    #pragma unroll
    for (int o = 32; o > 0; o >>= 1) {
        dp += __shfl_down(dp, o, 64);
        nq += __shfl_down(nq, o, 64);
    }
    if (lane == 0) coef[bs] = 1.0f + dp / (nq + 1e-12f);
}

// ---------------------------------------------------------------------------
// Softmax over S=256 + weighted fact sum -> att1/att2 [64][64]
// ---------------------------------------------------------------------------
__global__ __launch_bounds__(256) void k_attend(
    const int* __restrict__ click_his, const float* __restrict__ click_mask,
    const float* __restrict__ emb, const float* __restrict__ coef,
    const float* __restrict__ unatt,
    const float* __restrict__ scores_c, const float* __restrict__ scores_u,
    float* __restrict__ att1, float* __restrict__ att2)
{
    const int b = blockIdx.x, ty = blockIdx.y, t = threadIdx.x;
    const int lane = t & 63, wv = t >> 6;
    __shared__ float sa[SS];
    __shared__ float red[8];
    __shared__ float part[4][DD];

    const float sc = (ty ? scores_u : scores_c)[b * SS + t];
    float m = sc;
    #pragma unroll
    for (int o = 32; o > 0; o >>= 1) m = fmaxf(m, __shfl_down(m, o, 64));
    if (lane == 0) red[wv] = m;
    __syncthreads();
    m = fmaxf(fmaxf(red[0], red[1]), fmaxf(red[2], red[3]));
    const float e = __expf(sc - m);
    sa[t] = e;
    float s = e;
    #pragma unroll
    for (int o = 32; o > 0; o >>= 1) s += __shfl_down(s, o, 64);
    if (lane == 0) red[4 + wv] = s;
    __syncthreads();
    const float inv = 1.0f / (red[4] + red[5] + red[6] + red[7]);

    float acc = 0.0f;
    for (int s2 = wv * 64; s2 < wv * 64 + 64; ++s2) {
        const int bs = b * SS + s2;
        const float fv = ty ? unatt[bs * DD + lane]
                            : emb[(size_t)click_his[bs] * DD + lane] * click_mask[bs] * coef[bs];
        acc += sa[s2] * inv * fv;
    }
    part[wv][lane] = acc;
    __syncthreads();
    if (t < DD) {
        const float v = part[0][t] + part[1][t] + part[2][t] + part[3][t];
        (ty ? att2 : att1)[b * DD + t] = v;
    }
}

// ---------------------------------------------------------------------------
// Final head: BN + 192->200->80->2 PReLU MLP + softmax(+1e-8)
// ---------------------------------------------------------------------------
__global__ __launch_bounds__(256) void k_final(
    const int* __restrict__ mid, const float* __restrict__ emb,
    const float* __restrict__ att1, const float* __restrict__ att2,
    const float* __restrict__ bn_g, const float* __restrict__ bn_b,
    const float* __restrict__ bn_m, const float* __restrict__ bn_v,
    const float* __restrict__ fW1, const float* __restrict__ fb1, const float* __restrict__ a1,
    const float* __restrict__ fW2, const float* __restrict__ fb2, const float* __restrict__ a2,
    const float* __restrict__ fW3, const float* __restrict__ fb3,
    float* __restrict__ out)
{
    const int b = blockIdx.x;
    const int t = threadIdx.x;
    __shared__ float x[FF];
    __shared__ float h1[FH1];
    __shared__ float h2[FH2];

    if (t < DD) {
        x[t]          = emb[(size_t)mid[b] * DD + t];
        x[DD + t]     = att1[b * DD + t];
        x[2 * DD + t] = att2[b * DD + t];
    }
    __syncthreads();
    if (t < FF) x[t] = (x[t] - bn_m[t]) * rsqrtf(bn_v[t] + 1e-3f) * bn_g[t] + bn_b[t];
    __syncthreads();
    if (t < FH1) {
        float acc = fb1[t];
        #pragma unroll 4
        for (int i = 0; i < FF; ++i) acc += x[i] * fW1[i * FH1 + t];
        h1[t] = fmaxf(acc, 0.0f) + a1[t] * fminf(acc, 0.0f);
    }
    __syncthreads();
    if (t < FH2) {
        float acc = fb2[t];
        #pragma unroll 4
        for (int i = 0; i < FH1; ++i) acc += h1[i] * fW2[i * FH2 + t];
        h2[t] = fmaxf(acc, 0.0f) + a2[t] * fminf(acc, 0.0f);
    }
    __syncthreads();
    if (t == 0) {
        float l0 = fb3[0], l1 = fb3[1];
        for (int i = 0; i < FH2; ++i) {
            l0 += h2[i] * fW3[i * 2 + 0];
            l1 += h2[i] * fW3[i * 2 + 1];
        }
        const float mx = fmaxf(l0, l1);
        const float e0 = __expf(l0 - mx), e1 = __expf(l1 - mx);
        const float inv = 1.0f / (e0 + e1);
        out[b * 2 + 0] = e0 * inv + 1e-8f;
        out[b * 2 + 1] = e1 * inv + 1e-8f;
    }
}

// ---------------------------------------------------------------------------
extern "C" void kernel_launch(void* const* d_in, const int* in_sizes, int n_in,
                              void* d_out, int out_size, void* d_ws, size_t ws_size,
                              hipStream_t stream) {
    const int*   mid          = (const int*)d_in[0];
    const int*   click_his    = (const int*)d_in[1];
    const int*   unclick_his  = (const int*)d_in[2];
    const float* click_mask   = (const float*)d_in[3];
    const float* unclick_mask = (const float*)d_in[4];
    const float* emb          = (const float*)d_in[5];
    const float* sW1 = (const float*)d_in[6];  const float* sb1 = (const float*)d_in[7];
    const float* sW2 = (const float*)d_in[8];  const float* sb2 = (const float*)d_in[9];
    const float* sW3 = (const float*)d_in[10]; const float* sb3 = (const float*)d_in[11];
    const float* cW1 = (const float*)d_in[12]; const float* cb1 = (const float*)d_in[13];
    const float* cW2 = (const float*)d_in[14]; const float* cb2 = (const float*)d_in[15];
    const float* cW3 = (const float*)d_in[16]; const float* cb3 = (const float*)d_in[17];
    const float* uW1 = (const float*)d_in[18]; const float* ub1 = (const float*)d_in[19];
    const float* uW2 = (const float*)d_in[20]; const float* ub2 = (const float*)d_in[21];
    const float* uW3 = (const float*)d_in[22]; const float* ub3 = (const float*)d_in[23];
    const float* bn_g = (const float*)d_in[24]; const float* bn_b = (const float*)d_in[25];
    const float* bn_m = (const float*)d_in[26]; const float* bn_v = (const float*)d_in[27];
    const float* fW1 = (const float*)d_in[28]; const float* fb1 = (const float*)d_in[29];
    const float* a1  = (const float*)d_in[30];
    const float* fW2 = (const float*)d_in[31]; const float* fb2 = (const float*)d_in[32];
    const float* a2  = (const float*)d_in[33];
    const float* fW3 = (const float*)d_in[34]; const float* fb3 = (const float*)d_in[35];

    float* out = (float*)d_out;

    // Workspace layout (bytes, all 16B-aligned)
    char* w = (char*)d_ws;
    __bf16* W1t    = (__bf16*)(w + 0);        // 3*80*200 bf16  = 96000 B
    __bf16* W2t    = (__bf16*)(w + 96000);    // 3*48*104 bf16  = 29952 B
    float* scores_s = (float*)(w + 125952);   // 163840 f32     = 655360 B
    float* scores_c = (float*)(w + 781312);   // 16384 f32
    float* scores_u = (float*)(w + 846848);   // 16384 f32
    float* unatt    = (float*)(w + 912384);   // 16384*64 f32   = 4194304 B
    float* coef     = (float*)(w + 5106688);  // 16384 f32
    float* att1     = (float*)(w + 5172224);  // 64*64 f32
    float* att2     = (float*)(w + 5188608);  // 64*64 f32

    hipLaunchKernelGGL(k_prep, dim3(3), dim3(256), 0, stream,
        sW1, sW2, cW1, cW2, uW1, uW2, W1t, W2t);

    // DIN-1: unclick facts (M = 163840 rows)
    hipLaunchKernelGGL(k_din, dim3(163840 / 64), dim3(256), 0, stream,
        0, mid, click_his, unclick_his, click_mask, unclick_mask, emb, unatt, coef,
        W1t + 0 * 80 * XSTR, W2t + 0 * 48 * H1STR, sb1, sb2, sW3, sb3, scores_s);

    hipLaunchKernelGGL(k_reduceK, dim3(16384 / 4), dim3(256), 0, stream,
        click_his, unclick_his, click_mask, unclick_mask, emb, scores_s, unatt, coef);

    // DIN-2: item vs click*coef (M = 16384)
    hipLaunchKernelGGL(k_din, dim3(16384 / 64), dim3(256), 0, stream,
        1, mid, click_his, unclick_his, click_mask, unclick_mask, emb, unatt, coef,
        W1t + 1 * 80 * XSTR, W2t + 1 * 48 * H1STR, cb1, cb2, cW3, cb3, scores_c);

    // DIN-3: item vs un_att (M = 16384)
    hipLaunchKernelGGL(k_din, dim3(16384 / 64), dim3(256), 0, stream,
        2, mid, click_his, unclick_his, click_mask, unclick_mask, emb, unatt, coef,
        W1t + 2 * 80 * XSTR, W2t + 2 * 48 * H1STR, ub1, ub2, uW3, ub3, scores_u);

    hipLaunchKernelGGL(k_attend, dim3(BB, 2), dim3(256), 0, stream,
        click_his, click_mask, emb, coef, unatt, scores_c, scores_u, att1, att2);

    hipLaunchKernelGGL(k_final, dim3(BB), dim3(256), 0, stream,
        mid, emb, att1, att2, bn_g, bn_b, bn_m, bn_v,
        fW1, fb1, a1, fW2, fb2, a2, fW3, fb3, out);
}

// Round 3
// 271.255 us; speedup vs baseline: 4.0203x; 1.0594x over previous
//
#include <hip/hip_runtime.h>
#include <hip/hip_bf16.h>
#include <math.h>

// Problem constants
#define BB 64      // batch
#define SS 256     // click seq len
#define KK 10      // unclick per click
#define DD 64      // emb dim
#define FF 192     // 3*D
#define FH1 200
#define FH2 80
#define BIG_NEG_F (-4294967295.0f)

// LDS strides
#define XSTR 200   // X / W1t row stride in bf16 (192 + 8 pad)
#define H1STR 104  // h1 / W2t row stride in bf16 (96 + 8 pad)
#define H2STR 49   // h2 row stride in fp32 (odd -> conflict-free column reads)

// folded-weight region per MLP (bf16 elements): W1t [80][200] then W2t [48][104]
#define W1ELTS (80 * XSTR)          // 16000
#define W2ELTS (48 * H1STR)         // 4992
#define WREG   (W1ELTS + W2ELTS)    // 20992 bf16 = 41984 B (16B-aligned)

typedef __bf16 bfrag __attribute__((ext_vector_type(8)));
typedef float f32x4 __attribute__((ext_vector_type(4)));

__device__ __forceinline__ float sigm_(float x) { return 1.0f / (1.0f + __expf(-x)); }

// ---------------------------------------------------------------------------
// Prep: fold W1 (256x80) -> W1t[n][k]: k<64: W1a+W1c; 64..127: W1b-W1c;
// 128..191: W1d. W2 (80x40) -> W2t[n][k] zero-padded to [48][104].
// One block per MLP (s=0, c=1, u=2).
// ---------------------------------------------------------------------------
__global__ __launch_bounds__(256) void k_prep(
    const float* __restrict__ sW1, const float* __restrict__ sW2,
    const float* __restrict__ cW1, const float* __restrict__ cW2,
    const float* __restrict__ uW1, const float* __restrict__ uW2,
    __bf16* __restrict__ Wt)
{
    const int p = blockIdx.x;
    const float* W1 = (p == 0) ? sW1 : (p == 1) ? cW1 : uW1;   // [256][80]
    const float* W2 = (p == 0) ? sW2 : (p == 1) ? cW2 : uW2;   // [80][40]
    __bf16* o1 = Wt + p * WREG;
    __bf16* o2 = o1 + W1ELTS;
    for (int e = threadIdx.x; e < W1ELTS; e += 256) {
        const int n = e / XSTR, k = e % XSTR;
        float v = 0.0f;
        if (k < 64)       v = W1[k * 80 + n] + W1[(128 + k) * 80 + n];
        else if (k < 128) { const int kk = k - 64;  v = W1[(64 + kk) * 80 + n] - W1[(128 + kk) * 80 + n]; }
        else if (k < 192) { const int kk = k - 128; v = W1[(192 + kk) * 80 + n]; }
        o1[e] = (__bf16)v;
    }
    for (int e = threadIdx.x; e < W2ELTS; e += 256) {
        const int n = e / H1STR, k = e % H1STR;
        o2[e] = (__bf16)((n < 40 && k < 80) ? W2[k * 40 + n] : 0.0f);
    }
}

// ---------------------------------------------------------------------------
// Persistent fused DIN-0 + reduceK. Grid 512 x 320 threads (5 waves).
// Tile = 80 rows = 8 bs. Each block loops 4 tiles; weights staged once.
// Outputs: unatt[16384][64], coef[16384].
// ---------------------------------------------------------------------------
__global__ __launch_bounds__(320, 2) void k_din0(
    const int* __restrict__ click_his, const int* __restrict__ unclick_his,
    const float* __restrict__ click_mask, const float* __restrict__ unclick_mask,
    const float* __restrict__ emb, const __bf16* __restrict__ Wt,
    const float* __restrict__ b1, const float* __restrict__ b2,
    const float* __restrict__ W3, const float* __restrict__ b3,
    float* __restrict__ unatt, float* __restrict__ coef)
{
    __shared__ __align__(16) __bf16 sW1[80 * XSTR];   // 32000 B (persists)
    __shared__ __align__(16) __bf16 sW2[48 * H1STR];  // 9984 B (persists)
    __shared__ __align__(16) __bf16 sX [80 * XSTR];   // 32000 B (X -> H1 -> H2)
    __shared__ float ssc[80];

    const int t = threadIdx.x;
    const int wave = t >> 6, lane = t & 63;
    const int quad = lane >> 4, l15 = lane & 15;
    const int r  = t >> 2;            // row 0..79
    const int c0 = (t & 3) << 4;      // col chunk 0/16/32/48

    // ---- stage folded weights once ----
    {
        const uint4* s1 = (const uint4*)(Wt);
        uint4* d1 = (uint4*)sW1;
        for (int e = t; e < W1ELTS / 8; e += 320) d1[e] = s1[e];
        const uint4* s2 = (const uint4*)(Wt + W1ELTS);
        uint4* d2 = (uint4*)sW2;
        for (int e = t; e < W2ELTS / 8; e += 320) d2[e] = s2[e];
    }

    // ---- gather prefetch registers ----
    float4 pq[4], pf[4];
    float pqs, pfs;
    auto loadrow = [&](int tl) {
        const int m  = tl * 80 + r;          // row in [0, 163840)
        const int bs = tl * 8 + r / 10;
        const float* qp = emb + (size_t)click_his[bs] * DD;
        const float* fp = emb + (size_t)unclick_his[m] * DD;
        pqs = click_mask[bs];
        pfs = unclick_mask[m];
        #pragma unroll
        for (int i = 0; i < 4; ++i) {
            pq[i] = *(const float4*)(qp + c0 + 4 * i);
            pf[i] = *(const float4*)(fp + c0 + 4 * i);
        }
    };
    loadrow(blockIdx.x);

    for (int tile = blockIdx.x; tile < 2048; tile += 512) {
        // ---- write X = [q | f | q*f] as b128 stores ----
        {
            float qa[16], fa[16];
            #pragma unroll
            for (int i = 0; i < 4; ++i) {
                *(float4*)(qa + 4 * i) = pq[i];
                *(float4*)(fa + 4 * i) = pf[i];
            }
            __bf16* xr = sX + r * XSTR;
            #pragma unroll
            for (int h = 0; h < 2; ++h) {
                bfrag vq, vf, vm;
                #pragma unroll
                for (int j = 0; j < 8; ++j) {
                    const float qv = qa[h * 8 + j] * pqs;
                    const float fv = fa[h * 8 + j] * pfs;
                    vq[j] = (__bf16)qv; vf[j] = (__bf16)fv; vm[j] = (__bf16)(qv * fv);
                }
                *(bfrag*)(xr + c0 + h * 8)       = vq;
                *(bfrag*)(xr + 64 + c0 + h * 8)  = vf;
                *(bfrag*)(xr + 128 + c0 + h * 8) = vm;
            }
        }
        __syncthreads();                       // X ready

        if (tile + 512 < 2048) loadrow(tile + 512);   // prefetch next tile

        // ---- layer 1: [80x192] @ [192x80] ----
        bfrag af[6];
        {
            const __bf16* xrow = sX + (wave * 16 + l15) * XSTR + quad * 8;
            #pragma unroll
            for (int kc = 0; kc < 6; ++kc) af[kc] = *(const bfrag*)(xrow + kc * 32);
        }
        f32x4 acc[5];
        #pragma unroll
        for (int nt = 0; nt < 5; ++nt) acc[nt] = (f32x4){0.f, 0.f, 0.f, 0.f};
        {
            const __bf16* wbase = sW1 + l15 * XSTR + quad * 8;
            #pragma unroll
            for (int nt = 0; nt < 5; ++nt) {
                const __bf16* wp = wbase + nt * 16 * XSTR;
                #pragma unroll
                for (int kc = 0; kc < 6; ++kc)
                    acc[nt] = __builtin_amdgcn_mfma_f32_16x16x32_bf16(
                        af[kc], *(const bfrag*)(wp + kc * 32), acc[nt], 0, 0, 0);
            }
        }
        __syncthreads();                       // sX readers done

        // ---- sigmoid -> H1 (aliases sX), zero-pad cols [80,96) ----
        __bf16* sH1 = sX;
        #pragma unroll
        for (int nt = 0; nt < 5; ++nt) {
            const int n = nt * 16 + l15;
            const float bb = b1[n];
            #pragma unroll
            for (int rg = 0; rg < 4; ++rg) {
                const int row = wave * 16 + quad * 4 + rg;
                sH1[row * H1STR + n] = (__bf16)sigm_(acc[nt][rg] + bb);
            }
        }
        for (int e = t; e < 80 * 16; e += 320) {
            const int row = e >> 4, cc = 80 + (e & 15);
            sH1[row * H1STR + cc] = (__bf16)0.0f;
        }
        __syncthreads();                       // H1 ready

        // ---- layer 2: [80x96] @ [96x48] ----
        bfrag af2[3];
        {
            const __bf16* hrow = sH1 + (wave * 16 + l15) * H1STR + quad * 8;
            #pragma unroll
            for (int kc = 0; kc < 3; ++kc) af2[kc] = *(const bfrag*)(hrow + kc * 32);
        }
        f32x4 acc2[3];
        #pragma unroll
        for (int nt = 0; nt < 3; ++nt) acc2[nt] = (f32x4){0.f, 0.f, 0.f, 0.f};
        {
            const __bf16* wbase = sW2 + l15 * H1STR + quad * 8;
            #pragma unroll
            for (int nt = 0; nt < 3; ++nt) {
                const __bf16* wp = wbase + nt * 16 * H1STR;
                #pragma unroll
                for (int kc = 0; kc < 3; ++kc)
                    acc2[nt] = __builtin_amdgcn_mfma_f32_16x16x32_bf16(
                        af2[kc], *(const bfrag*)(wp + kc * 32), acc2[nt], 0, 0, 0);
            }
        }
        __syncthreads();                       // H1 readers done

        // ---- sigmoid -> H2 fp32 (aliases sX front) ----
        float* sH2 = (float*)sX;
        #pragma unroll
        for (int nt = 0; nt < 3; ++nt) {
            const int n = nt * 16 + l15;
            if (n < 40) {
                const float bb = b2[n];
                #pragma unroll
                for (int rg = 0; rg < 4; ++rg) {
                    const int row = wave * 16 + quad * 4 + rg;
                    sH2[row * H2STR + n] = sigm_(acc2[nt][rg] + bb);
                }
            }
        }
        __syncthreads();                       // H2 ready

        // ---- layer 3: dot-40 + mask -> ssc ----
        if (t < 80) {
            float s = b3[0];
            #pragma unroll 8
            for (int i = 0; i < 40; ++i) s += sH2[t * H2STR + i] * W3[i];
            const int m = tile * 80 + t;
            ssc[t] = (unclick_mask[m] == 1.0f) ? s : BIG_NEG_F;
        }
        __syncthreads();                       // ssc ready

        // ---- fused reduceK: softmax over K, unatt, coef ----
        for (int j = wave; j < 8; j += 5) {
            const int bs = tile * 8 + j;
            float a[KK];
            float mx = -INFINITY;
            #pragma unroll
            for (int k = 0; k < KK; ++k) { a[k] = ssc[j * KK + k]; mx = fmaxf(mx, a[k]); }
            float sum = 0.0f;
            #pragma unroll
            for (int k = 0; k < KK; ++k) { a[k] = __expf(a[k] - mx); sum += a[k]; }
            const float inv = 1.0f / sum;
            float acc3 = 0.0f;
            #pragma unroll
            for (int k = 0; k < KK; ++k) {
                const int off = bs * KK + k;
                acc3 += a[k] * (emb[(size_t)unclick_his[off] * DD + lane] * unclick_mask[off]);
            }
            acc3 *= inv;
            unatt[bs * DD + lane] = acc3;
            const float qv = emb[(size_t)click_his[bs] * DD + lane] * click_mask[bs];
            float dp = acc3 * qv, nq = qv * qv;
            #pragma unroll
            for (int o = 32; o > 0; o >>= 1) {
                dp += __shfl_down(dp, o, 64);
                nq += __shfl_down(nq, o, 64);
            }
            if (lane == 0) coef[bs] = 1.0f + dp / (nq + 1e-12f);
        }
        __syncthreads();                       // tail done; sX reusable
    }
}

// ---------------------------------------------------------------------------
// DIN-1 + DIN-2 in one launch: grid (256, 2), 256 threads, 64-row tiles.
// blockIdx.y: 0 -> mode1 (q=item, f=click*coef, cW*), 1 -> mode2 (f=un_att, uW*)
// ---------------------------------------------------------------------------
__global__ __launch_bounds__(256, 2) void k_din12(
    const int* __restrict__ mid, const int* __restrict__ click_his,
    const float* __restrict__ click_mask,
    const float* __restrict__ emb, const float* __restrict__ unatt,
    const float* __restrict__ coef, const __bf16* __restrict__ Wt,
    const float* __restrict__ cb1, const float* __restrict__ cb2,
    const float* __restrict__ cW3, const float* __restrict__ cb3,
    const float* __restrict__ ub1, const float* __restrict__ ub2,
    const float* __restrict__ uW3, const float* __restrict__ ub3,
    float* __restrict__ scores_c, float* __restrict__ scores_u)
{
    __shared__ __align__(16) __bf16 sW1[80 * XSTR];
    __shared__ __align__(16) __bf16 sW2[48 * H1STR];
    __shared__ __align__(16) __bf16 sX [64 * XSTR];

    const int t = threadIdx.x;
    const int mode = blockIdx.y;     // 0 = c, 1 = u
    const int wave = t >> 6, lane = t & 63;
    const int quad = lane >> 4, l15 = lane & 15;

    const float* b1 = mode ? ub1 : cb1;
    const float* b2 = mode ? ub2 : cb2;
    const float* W3 = mode ? uW3 : cW3;
    const float* b3 = mode ? ub3 : cb3;
    const __bf16* wreg = Wt + (mode + 1) * WREG;

    // stage weights
    {
        const uint4* s1 = (const uint4*)(wreg);
        uint4* d1 = (uint4*)sW1;
        for (int e = t; e < W1ELTS / 8; e += 256) d1[e] = s1[e];
        const uint4* s2 = (const uint4*)(wreg + W1ELTS);
        uint4* d2 = (uint4*)sW2;
        for (int e = t; e < W2ELTS / 8; e += 256) d2[e] = s2[e];
    }

    // build X
    {
        const int r  = t >> 2;
        const int c0 = (t & 3) << 4;
        const int m  = blockIdx.x * 64 + r;
        const int b  = m >> 8;
        const float* qp = emb + (size_t)mid[b] * DD;
        const float* fp; float fs;
        if (mode == 0) { fp = emb + (size_t)click_his[m] * DD; fs = click_mask[m] * coef[m]; }
        else           { fp = unatt + (size_t)m * DD; fs = 1.0f; }
        float qa[16], fa[16];
        #pragma unroll
        for (int i = 0; i < 4; ++i) {
            *(float4*)(qa + 4 * i) = *(const float4*)(qp + c0 + 4 * i);
            *(float4*)(fa + 4 * i) = *(const float4*)(fp + c0 + 4 * i);
        }
        __bf16* xr = sX + r * XSTR;
        #pragma unroll
        for (int h = 0; h < 2; ++h) {
            bfrag vq, vf, vm;
            #pragma unroll
            for (int j = 0; j < 8; ++j) {
                const float qv = qa[h * 8 + j];
                const float fv = fa[h * 8 + j] * fs;
                vq[j] = (__bf16)qv; vf[j] = (__bf16)fv; vm[j] = (__bf16)(qv * fv);
            }
            *(bfrag*)(xr + c0 + h * 8)       = vq;
            *(bfrag*)(xr + 64 + c0 + h * 8)  = vf;
            *(bfrag*)(xr + 128 + c0 + h * 8) = vm;
        }
    }
    __syncthreads();

    // layer 1
    bfrag af[6];
    {
        const __bf16* xrow = sX + (wave * 16 + l15) * XSTR + quad * 8;
        #pragma unroll
        for (int kc = 0; kc < 6; ++kc) af[kc] = *(const bfrag*)(xrow + kc * 32);
    }
    f32x4 acc[5];
    #pragma unroll
    for (int nt = 0; nt < 5; ++nt) acc[nt] = (f32x4){0.f, 0.f, 0.f, 0.f};
    {
        const __bf16* wbase = sW1 + l15 * XSTR + quad * 8;
        #pragma unroll
        for (int nt = 0; nt < 5; ++nt) {
            const __bf16* wp = wbase + nt * 16 * XSTR;
            #pragma unroll
            for (int kc = 0; kc < 6; ++kc)
                acc[nt] = __builtin_amdgcn_mfma_f32_16x16x32_bf16(
                    af[kc], *(const bfrag*)(wp + kc * 32), acc[nt], 0, 0, 0);
        }
    }
    __syncthreads();

    __bf16* sH1 = sX;
    #pragma unroll
    for (int nt = 0; nt < 5; ++nt) {
        const int n = nt * 16 + l15;
        const float bb = b1[n];
        #pragma unroll
        for (int rg = 0; rg < 4; ++rg) {
            const int row = wave * 16 + quad * 4 + rg;
            sH1[row * H1STR + n] = (__bf16)sigm_(acc[nt][rg] + bb);
        }
    }
    for (int e = t; e < 64 * 16; e += 256) {
        const int row = e >> 4, cc = 80 + (e & 15);
        sH1[row * H1STR + cc] = (__bf16)0.0f;
    }
    __syncthreads();

    // layer 2
    bfrag af2[3];
    {
        const __bf16* hrow = sH1 + (wave * 16 + l15) * H1STR + quad * 8;
        #pragma unroll
        for (int kc = 0; kc < 3; ++kc) af2[kc] = *(const bfrag*)(hrow + kc * 32);
    }
    f32x4 acc2[3];
    #pragma unroll
    for (int nt = 0; nt < 3; ++nt) acc2[nt] = (f32x4){0.f, 0.f, 0.f, 0.f};
    {
        const __bf16* wbase = sW2 + l15 * H1STR + quad * 8;
        #pragma unroll
        for (int nt = 0; nt < 3; ++nt) {
            const __bf16* wp = wbase + nt * 16 * H1STR;
            #pragma unroll
            for (int kc = 0; kc < 3; ++kc)
                acc2[nt] = __builtin_amdgcn_mfma_f32_16x16x32_bf16(
                    af2[kc], *(const bfrag*)(wp + kc * 32), acc2[nt], 0, 0, 0);
        }
    }
    __syncthreads();

    float* sH2 = (float*)sX;
    #pragma unroll
    for (int nt = 0; nt < 3; ++nt) {
        const int n = nt * 16 + l15;
        if (n < 40) {
            const float bb = b2[n];
            #pragma unroll
            for (int rg = 0; rg < 4; ++rg) {
                const int row = wave * 16 + quad * 4 + rg;
                sH2[row * H2STR + n] = sigm_(acc2[nt][rg] + bb);
            }
        }
    }
    __syncthreads();

    if (t < 64) {
        float s = b3[0];
        #pragma unroll 8
        for (int i = 0; i < 40; ++i) s += sH2[t * H2STR + i] * W3[i];
        const int m = blockIdx.x * 64 + t;
        const float sc = (click_mask[m] == 1.0f) ? s : BIG_NEG_F;
        (mode ? scores_u : scores_c)[m] = sc;
    }
}

// ---------------------------------------------------------------------------
// Tail: per-b softmax over S=256 (x2), weighted fact sums, BN + final MLP
// ---------------------------------------------------------------------------
__global__ __launch_bounds__(256) void k_tail(
    const int* __restrict__ mid, const int* __restrict__ click_his,
    const float* __restrict__ click_mask,
    const float* __restrict__ emb, const float* __restrict__ unatt,
    const float* __restrict__ coef,
    const float* __restrict__ scores_c, const float* __restrict__ scores_u,
    const float* __restrict__ bn_g, const float* __restrict__ bn_b,
    const float* __restrict__ bn_m, const float* __restrict__ bn_v,
    const float* __restrict__ fW1, const float* __restrict__ fb1, const float* __restrict__ a1,
    const float* __restrict__ fW2, const float* __restrict__ fb2, const float* __restrict__ a2,
    const float* __restrict__ fW3, const float* __restrict__ fb3,
    float* __restrict__ out)
{
    const int b = blockIdx.x, t = threadIdx.x;
    const int lane = t & 63, wv = t >> 6;

    __shared__ float x[FF];
    __shared__ float sa[SS];
    __shared__ float red[8];
    __shared__ float part[4][DD];
    __shared__ float h1[FH1];
    __shared__ float h2[FH2];

    if (t < DD) x[t] = emb[(size_t)mid[b] * DD + t];

    for (int ty = 0; ty < 2; ++ty) {
        const float sc = (ty ? scores_u : scores_c)[b * SS + t];
        float m = sc;
        #pragma unroll
        for (int o = 32; o > 0; o >>= 1) m = fmaxf(m, __shfl_down(m, o, 64));
        if (lane == 0) red[wv] = m;
        __syncthreads();
        m = fmaxf(fmaxf(red[0], red[1]), fmaxf(red[2], red[3]));
        const float e = __expf(sc - m);
        sa[t] = e;
        float s = e;
        #pragma unroll
        for (int o = 32; o > 0; o >>= 1) s += __shfl_down(s, o, 64);
        if (lane == 0) red[4 + wv] = s;
        __syncthreads();
        const float inv = 1.0f / (red[4] + red[5] + red[6] + red[7]);

        float acc = 0.0f;
        for (int s2 = wv * 64; s2 < wv * 64 + 64; ++s2) {
            const int bs = b * SS + s2;
            const float fv = ty ? unatt[(size_t)bs * DD + lane]
                                : emb[(size_t)click_his[bs] * DD + lane] * click_mask[bs] * coef[bs];
            acc += sa[s2] * inv * fv;
        }
        part[wv][lane] = acc;
        __syncthreads();
        if (t < DD) x[DD + ty * DD + t] = part[0][t] + part[1][t] + part[2][t] + part[3][t];
        __syncthreads();
    }

    if (t < FF) x[t] = (x[t] - bn_m[t]) * rsqrtf(bn_v[t] + 1e-3f) * bn_g[t] + bn_b[t];
    __syncthreads();
    if (t < FH1) {
        float acc = fb1[t];
        #pragma unroll 4
        for (int i = 0; i < FF; ++i) acc += x[i] * fW1[i * FH1 + t];
        h1[t] = fmaxf(acc, 0.0f) + a1[t] * fminf(acc, 0.0f);
    }
    __syncthreads();
    if (t < FH2) {
        float acc = fb2[t];
        #pragma unroll 4
        for (int i = 0; i < FH1; ++i) acc += h1[i] * fW2[i * FH2 + t];
        h2[t] = fmaxf(acc, 0.0f) + a2[t] * fminf(acc, 0.0f);
    }
    __syncthreads();
    if (t == 0) {
        float l0 = fb3[0], l1 = fb3[1];
        for (int i = 0; i < FH2; ++i) {
            l0 += h2[i] * fW3[i * 2 + 0];
            l1 += h2[i] * fW3[i * 2 + 1];
        }
        const float mx = fmaxf(l0, l1);
        const float e0 = __expf(l0 - mx), e1 = __expf(l1 - mx);
        const float inv = 1.0f / (e0 + e1);
        out[b * 2 + 0] = e0 * inv + 1e-8f;
        out[b * 2 + 1] = e1 * inv + 1e-8f;
    }
}

// ---------------------------------------------------------------------------
extern "C" void kernel_launch(void* const* d_in, const int* in_sizes, int n_in,
                              void* d_out, int out_size, void* d_ws, size_t ws_size,
                              hipStream_t stream) {
    const int*   mid          = (const int*)d_in[0];
    const int*   click_his    = (const int*)d_in[1];
    const int*   unclick_his  = (const int*)d_in[2];
    const float* click_mask   = (const float*)d_in[3];
    const float* unclick_mask = (const float*)d_in[4];
    const float* emb          = (const float*)d_in[5];
    const float* sW1 = (const float*)d_in[6];  const float* sb1 = (const float*)d_in[7];
    const float* sW2 = (const float*)d_in[8];  const float* sb2 = (const float*)d_in[9];
    const float* sW3 = (const float*)d_in[10]; const float* sb3 = (const float*)d_in[11];
    const float* cW1 = (const float*)d_in[12]; const float* cb1 = (const float*)d_in[13];
    const float* cW2 = (const float*)d_in[14]; const float* cb2 = (const float*)d_in[15];
    const float* cW3 = (const float*)d_in[16]; const float* cb3 = (const float*)d_in[17];
    const float* uW1 = (const float*)d_in[18]; const float* ub1 = (const float*)d_in[19];
    const float* uW2 = (const float*)d_in[20]; const float* ub2 = (const float*)d_in[21];
    const float* uW3 = (const float*)d_in[22]; const float* ub3 = (const float*)d_in[23];
    const float* bn_g = (const float*)d_in[24]; const float* bn_b = (const float*)d_in[25];
    const float* bn_m = (const float*)d_in[26]; const float* bn_v = (const float*)d_in[27];
    const float* fW1 = (const float*)d_in[28]; const float* fb1 = (const float*)d_in[29];
    const float* a1  = (const float*)d_in[30];
    const float* fW2 = (const float*)d_in[31]; const float* fb2 = (const float*)d_in[32];
    const float* a2  = (const float*)d_in[33];
    const float* fW3 = (const float*)d_in[34]; const float* fb3 = (const float*)d_in[35];

    float* out = (float*)d_out;

    // Workspace layout (bytes, 16B-aligned)
    char* w = (char*)d_ws;
    __bf16* Wt      = (__bf16*)(w + 0);       // 3*41984 = 125952 B
    float* scores_c = (float*)(w + 125952);   // 16384 f32 = 65536 B
    float* scores_u = (float*)(w + 191488);   // 65536 B
    float* coef     = (float*)(w + 257024);   // 65536 B
    float* unatt    = (float*)(w + 322560);   // 16384*64 f32 = 4194304 B
    // total 4516864 B

    hipLaunchKernelGGL(k_prep, dim3(3), dim3(256), 0, stream,
        sW1, sW2, cW1, cW2, uW1, uW2, Wt);

    hipLaunchKernelGGL(k_din0, dim3(512), dim3(320), 0, stream,
        click_his, unclick_his, click_mask, unclick_mask, emb, Wt,
        sb1, sb2, sW3, sb3, unatt, coef);

    hipLaunchKernelGGL(k_din12, dim3(256, 2), dim3(256), 0, stream,
        mid, click_his, click_mask, emb, unatt, coef, Wt,
        cb1, cb2, cW3, cb3, ub1, ub2, uW3, ub3, scores_c, scores_u);

    hipLaunchKernelGGL(k_tail, dim3(BB), dim3(256), 0, stream,
        mid, click_his, click_mask, emb, unatt, coef, scores_c, scores_u,
        bn_g, bn_b, bn_m, bn_v, fW1, fb1, a1, fW2, fb2, a2, fW3, fb3, out);
}

// Round 4
// 235.564 us; speedup vs baseline: 4.6294x; 1.1515x over previous
//
#include <hip/hip_runtime.h>
#include <hip/hip_bf16.h>
#include <math.h>

// Problem constants
#define BB 64      // batch
#define SS 256     // click seq len
#define KK 10      // unclick per click
#define DD 64      // emb dim
#define FF 192     // 3*D
#define FH1 200
#define FH2 80
#define BIG_NEG_F (-4294967295.0f)

// LDS strides
#define XSTR 200   // W1t row stride in bf16 (192 + 8 pad)  [stride 100 dw -> 2-way free]
#define H1STR 104  // H1 / W2t row stride in bf16 (96 + 8 pad) [52 dw -> 2-way free]

// folded-weight region per MLP (bf16 elements)
#define W1ELTS (80 * XSTR)          // 16000
#define W2ELTS (48 * H1STR)         // 4992
#define WREG   (W1ELTS + W2ELTS)    // 20992 bf16 = 41984 B (16B-aligned)

typedef __bf16 bfrag __attribute__((ext_vector_type(8)));
typedef float f32x4 __attribute__((ext_vector_type(4)));

__device__ __forceinline__ float sigm_(float x) { return 1.0f / (1.0f + __expf(-x)); }

// ---------------------------------------------------------------------------
// Prep: fold W1 (256x80) -> W1t[n][k]: k<64: W1a+W1c; 64..127: W1b-W1c;
// 128..191: W1d. W2 (80x40) -> W2t[n][k] zero-padded to [48][104].
// Grid (3, 10) for parallelism.
// ---------------------------------------------------------------------------
__global__ __launch_bounds__(256) void k_prep(
    const float* __restrict__ sW1, const float* __restrict__ sW2,
    const float* __restrict__ cW1, const float* __restrict__ cW2,
    const float* __restrict__ uW1, const float* __restrict__ uW2,
    __bf16* __restrict__ Wt)
{
    const int p = blockIdx.x, g = blockIdx.y;
    const float* W1 = (p == 0) ? sW1 : (p == 1) ? cW1 : uW1;   // [256][80]
    const float* W2 = (p == 0) ? sW2 : (p == 1) ? cW2 : uW2;   // [80][40]
    __bf16* o1 = Wt + p * WREG;
    __bf16* o2 = o1 + W1ELTS;
    for (int e = g * 256 + threadIdx.x; e < W1ELTS; e += 2560) {
        const int n = e / XSTR, k = e % XSTR;
        float v = 0.0f;
        if (k < 64)       v = W1[k * 80 + n] + W1[(128 + k) * 80 + n];
        else if (k < 128) { const int kk = k - 64;  v = W1[(64 + kk) * 80 + n] - W1[(128 + kk) * 80 + n]; }
        else if (k < 192) { const int kk = k - 128; v = W1[(192 + kk) * 80 + n]; }
        o1[e] = (__bf16)v;
    }
    for (int e = g * 256 + threadIdx.x; e < W2ELTS; e += 2560) {
        const int n = e / H1STR, k = e % H1STR;
        o2[e] = (__bf16)((n < 40 && k < 80) ? W2[k * 40 + n] : 0.0f);
    }
}

// ---------------------------------------------------------------------------
// Wave-level MLP core: rows m = l15 (one 16-row tile), A-fragments built in
// registers from qv/fv (lane (quad,l15) holds cols quad*8..+7 and 32+quad*8..+7
// of its row, pre-scaled). Layer1 B from shared sW1; H1 round-trips through a
// wave-PRIVATE LDS slice (no barrier); layer2 B from registers; layer3 dot via
// shfl butterfly. Returns score[rg] (rows quad*4+rg) valid on l15==0 lanes.
// ---------------------------------------------------------------------------
__device__ __forceinline__ void mlp_core(
    const float* qv, const float* fv,
    const __bf16* __restrict__ sW1, __bf16* __restrict__ sH1w,
    const bfrag* wb2, const float* b1v, const float* b2v, const float* w3v,
    int quad, int l15, float* score)
{
    // build A fragments
    bfrag af[6];
    #pragma unroll
    for (int j = 0; j < 8; ++j) {
        af[0][j] = (__bf16)qv[j];
        af[1][j] = (__bf16)qv[8 + j];
        af[2][j] = (__bf16)fv[j];
        af[3][j] = (__bf16)fv[8 + j];
        af[4][j] = (__bf16)(qv[j] * fv[j]);
        af[5][j] = (__bf16)(qv[8 + j] * fv[8 + j]);
    }

    // layer 1: [16x192] @ [192x80]
    f32x4 acc[5];
    #pragma unroll
    for (int nt = 0; nt < 5; ++nt) acc[nt] = (f32x4){0.f, 0.f, 0.f, 0.f};
    {
        const __bf16* wbase = sW1 + l15 * XSTR + quad * 8;
        #pragma unroll
        for (int nt = 0; nt < 5; ++nt) {
            const __bf16* wp = wbase + nt * 16 * XSTR;
            #pragma unroll
            for (int kc = 0; kc < 6; ++kc)
                acc[nt] = __builtin_amdgcn_mfma_f32_16x16x32_bf16(
                    af[kc], *(const bfrag*)(wp + kc * 32), acc[nt], 0, 0, 0);
        }
    }

    // sigmoid -> wave-private H1 slice; zero-pad cols [80,96)
    #pragma unroll
    for (int nt = 0; nt < 5; ++nt) {
        #pragma unroll
        for (int rg = 0; rg < 4; ++rg)
            sH1w[(quad * 4 + rg) * H1STR + nt * 16 + l15] =
                (__bf16)sigm_(acc[nt][rg] + b1v[nt]);
    }
    #pragma unroll
    for (int rg = 0; rg < 4; ++rg)
        sH1w[(quad * 4 + rg) * H1STR + 80 + l15] = (__bf16)0.0f;

    // layer 2: [16x96] @ [96x48]  (A from private slice; compiler orders via lgkmcnt)
    bfrag af2[3];
    {
        const __bf16* hrow = sH1w + l15 * H1STR + quad * 8;
        #pragma unroll
        for (int kc = 0; kc < 3; ++kc) af2[kc] = *(const bfrag*)(hrow + kc * 32);
    }
    f32x4 acc2[3];
    #pragma unroll
    for (int nt = 0; nt < 3; ++nt) acc2[nt] = (f32x4){0.f, 0.f, 0.f, 0.f};
    #pragma unroll
    for (int nt = 0; nt < 3; ++nt)
        #pragma unroll
        for (int kc = 0; kc < 3; ++kc)
            acc2[nt] = __builtin_amdgcn_mfma_f32_16x16x32_bf16(
                af2[kc], wb2[nt * 3 + kc], acc2[nt], 0, 0, 0);

    // layer 3: per-lane partial dot + butterfly over the 16-lane group
    float part[4] = {0.f, 0.f, 0.f, 0.f};
    #pragma unroll
    for (int nt = 0; nt < 3; ++nt) {
        #pragma unroll
        for (int rg = 0; rg < 4; ++rg)
            part[rg] += sigm_(acc2[nt][rg] + b2v[nt]) * w3v[nt];
    }
    #pragma unroll
    for (int off = 1; off < 16; off <<= 1) {
        #pragma unroll
        for (int rg = 0; rg < 4; ++rg)
            part[rg] += __shfl_xor(part[rg], off, 64);
    }
    #pragma unroll
    for (int rg = 0; rg < 4; ++rg) score[rg] = part[rg];
}

// ---------------------------------------------------------------------------
// DIN-0 + fused reduceK. Grid 2048 x 320 threads (5 waves), tile = 80 rows = 8 bs.
// Barriers: 1 (weights) + 1 (ssc) per block.
// ---------------------------------------------------------------------------
__global__ __launch_bounds__(320) void k_din0(
    const int* __restrict__ click_his, const int* __restrict__ unclick_his,
    const float* __restrict__ click_mask, const float* __restrict__ unclick_mask,
    const float* __restrict__ emb, const __bf16* __restrict__ Wt,
    const float* __restrict__ b1, const float* __restrict__ b2,
    const float* __restrict__ W3, const float* __restrict__ b3,
    float* __restrict__ unatt, float* __restrict__ coef)
{
    __shared__ __align__(16) __bf16 sW1[80 * XSTR];        // 32000 B
    __shared__ __align__(16) __bf16 sH1[5 * 16 * H1STR];   // 16640 B
    __shared__ float ssc[80];

    const int t = threadIdx.x;
    const int wave = t >> 6, lane = t & 63;
    const int quad = lane >> 4, l15 = lane & 15;

    // stage W1 (shared)
    {
        const uint4* s1 = (const uint4*)Wt;
        uint4* d1 = (uint4*)sW1;
        for (int e = t; e < W1ELTS / 8; e += 320) d1[e] = s1[e];
    }

    // per-wave register weights
    bfrag wb2[9];
    float b1v[5], b2v[3], w3v[3];
    {
        const __bf16* w2g = Wt + W1ELTS;
        #pragma unroll
        for (int nt = 0; nt < 3; ++nt)
            #pragma unroll
            for (int kc = 0; kc < 3; ++kc)
                wb2[nt * 3 + kc] = *(const bfrag*)(w2g + (nt * 16 + l15) * H1STR + kc * 32 + quad * 8);
        #pragma unroll
        for (int nt = 0; nt < 5; ++nt) b1v[nt] = b1[nt * 16 + l15];
        #pragma unroll
        for (int nt = 0; nt < 3; ++nt) {
            const int n = nt * 16 + l15;
            b2v[nt] = (n < 40) ? b2[n] : 0.0f;
            w3v[nt] = (n < 40) ? W3[n] : 0.0f;
        }
    }
    const float b3v = b3[0];

    // gather X slices into registers (lane's MFMA A-slice of its row)
    const int row = 16 * wave + l15;                 // 0..79
    const int m   = blockIdx.x * 80 + row;
    const int bs  = blockIdx.x * 8 + row / 10;
    float qv[16], fv[16];
    {
        const float* qp = emb + (size_t)click_his[bs] * DD;
        const float* fp = emb + (size_t)unclick_his[m] * DD;
        const float qs = click_mask[bs], fs = unclick_mask[m];
        const int c = quad * 8;
        *(float4*)(qv + 0)  = *(const float4*)(qp + c);
        *(float4*)(qv + 4)  = *(const float4*)(qp + c + 4);
        *(float4*)(qv + 8)  = *(const float4*)(qp + 32 + c);
        *(float4*)(qv + 12) = *(const float4*)(qp + 32 + c + 4);
        *(float4*)(fv + 0)  = *(const float4*)(fp + c);
        *(float4*)(fv + 4)  = *(const float4*)(fp + c + 4);
        *(float4*)(fv + 8)  = *(const float4*)(fp + 32 + c);
        *(float4*)(fv + 12) = *(const float4*)(fp + 32 + c + 4);
        #pragma unroll
        for (int i = 0; i < 16; ++i) { qv[i] *= qs; fv[i] *= fs; }
    }
    __syncthreads();   // weights staged

    float score[4];
    mlp_core(qv, fv, sW1, sH1 + wave * 16 * H1STR, wb2, b1v, b2v, w3v, quad, l15, score);

    if (l15 == 0) {
        #pragma unroll
        for (int rg = 0; rg < 4; ++rg) {
            const int r2 = 16 * wave + quad * 4 + rg;
            const int m2 = blockIdx.x * 80 + r2;
            ssc[r2] = (unclick_mask[m2] == 1.0f) ? (score[rg] + b3v) : BIG_NEG_F;
        }
    }
    __syncthreads();   // ssc ready

    // fused reduceK: softmax over K, unatt, coef (wave w handles bs j = w, w+5)
    for (int j = wave; j < 8; j += 5) {
        const int bsj = blockIdx.x * 8 + j;
        float a[KK];
        float mx = -INFINITY;
        #pragma unroll
        for (int k = 0; k < KK; ++k) { a[k] = ssc[j * KK + k]; mx = fmaxf(mx, a[k]); }
        float sum = 0.0f;
        #pragma unroll
        for (int k = 0; k < KK; ++k) { a[k] = __expf(a[k] - mx); sum += a[k]; }
        const float inv = 1.0f / sum;
        float acc3 = 0.0f;
        #pragma unroll
        for (int k = 0; k < KK; ++k) {
            const int off = bsj * KK + k;
            acc3 += a[k] * (emb[(size_t)unclick_his[off] * DD + lane] * unclick_mask[off]);
        }
        acc3 *= inv;
        unatt[(size_t)bsj * DD + lane] = acc3;
        const float qv2 = emb[(size_t)click_his[bsj] * DD + lane] * click_mask[bsj];
        float dp = acc3 * qv2, nq = qv2 * qv2;
        #pragma unroll
        for (int o = 32; o > 0; o >>= 1) {
            dp += __shfl_down(dp, o, 64);
            nq += __shfl_down(nq, o, 64);
        }
        if (lane == 0) coef[bsj] = 1.0f + dp / (nq + 1e-12f);
    }
}

// ---------------------------------------------------------------------------
// DIN-1 + DIN-2: grid (256, 2), 256 threads (4 waves), 64 rows/block.
// blockIdx.y: 0 -> (q=item, f=click*coef, cW*), 1 -> (f=un_att, uW*)
// Barriers: 1 (weights).
// ---------------------------------------------------------------------------
__global__ __launch_bounds__(256) void k_din12(
    const int* __restrict__ mid, const int* __restrict__ click_his,
    const float* __restrict__ click_mask,
    const float* __restrict__ emb, const float* __restrict__ unatt,
    const float* __restrict__ coef, const __bf16* __restrict__ Wt,
    const float* __restrict__ cb1, const float* __restrict__ cb2,
    const float* __restrict__ cW3, const float* __restrict__ cb3,
    const float* __restrict__ ub1, const float* __restrict__ ub2,
    const float* __restrict__ uW3, const float* __restrict__ ub3,
    float* __restrict__ scores_c, float* __restrict__ scores_u)
{
    __shared__ __align__(16) __bf16 sW1[80 * XSTR];        // 32000 B
    __shared__ __align__(16) __bf16 sH1[4 * 16 * H1STR];   // 13312 B

    const int t = threadIdx.x;
    const int mode = blockIdx.y;
    const int wave = t >> 6, lane = t & 63;
    const int quad = lane >> 4, l15 = lane & 15;

    const float* b1 = mode ? ub1 : cb1;
    const float* b2 = mode ? ub2 : cb2;
    const float* W3 = mode ? uW3 : cW3;
    const float* b3 = mode ? ub3 : cb3;
    const __bf16* wreg = Wt + (mode + 1) * WREG;

    {
        const uint4* s1 = (const uint4*)wreg;
        uint4* d1 = (uint4*)sW1;
        for (int e = t; e < W1ELTS / 8; e += 256) d1[e] = s1[e];
    }

    bfrag wb2[9];
    float b1v[5], b2v[3], w3v[3];
    {
        const __bf16* w2g = wreg + W1ELTS;
        #pragma unroll
        for (int nt = 0; nt < 3; ++nt)
            #pragma unroll
            for (int kc = 0; kc < 3; ++kc)
                wb2[nt * 3 + kc] = *(const bfrag*)(w2g + (nt * 16 + l15) * H1STR + kc * 32 + quad * 8);
        #pragma unroll
        for (int nt = 0; nt < 5; ++nt) b1v[nt] = b1[nt * 16 + l15];
        #pragma unroll
        for (int nt = 0; nt < 3; ++nt) {
            const int n = nt * 16 + l15;
            b2v[nt] = (n < 40) ? b2[n] : 0.0f;
            w3v[nt] = (n < 40) ? W3[n] : 0.0f;
        }
    }
    const float b3v = b3[0];

    const int row = 16 * wave + l15;
    const int m   = blockIdx.x * 64 + row;
    const int b   = m >> 8;
    float qv[16], fv[16];
    {
        const float* qp = emb + (size_t)mid[b] * DD;
        const float* fp; float fs;
        if (mode == 0) { fp = emb + (size_t)click_his[m] * DD; fs = click_mask[m] * coef[m]; }
        else           { fp = unatt + (size_t)m * DD; fs = 1.0f; }
        const int c = quad * 8;
        *(float4*)(qv + 0)  = *(const float4*)(qp + c);
        *(float4*)(qv + 4)  = *(const float4*)(qp + c + 4);
        *(float4*)(qv + 8)  = *(const float4*)(qp + 32 + c);
        *(float4*)(qv + 12) = *(const float4*)(qp + 32 + c + 4);
        *(float4*)(fv + 0)  = *(const float4*)(fp + c);
        *(float4*)(fv + 4)  = *(const float4*)(fp + c + 4);
        *(float4*)(fv + 8)  = *(const float4*)(fp + 32 + c);
        *(float4*)(fv + 12) = *(const float4*)(fp + 32 + c + 4);
        #pragma unroll
        for (int i = 0; i < 16; ++i) fv[i] *= fs;
    }
    __syncthreads();   // weights staged

    float score[4];
    mlp_core(qv, fv, sW1, sH1 + wave * 16 * H1STR, wb2, b1v, b2v, w3v, quad, l15, score);

    if (l15 == 0) {
        float* dst = mode ? scores_u : scores_c;
        #pragma unroll
        for (int rg = 0; rg < 4; ++rg) {
            const int m2 = blockIdx.x * 64 + 16 * wave + quad * 4 + rg;
            dst[m2] = (click_mask[m2] == 1.0f) ? (score[rg] + b3v) : BIG_NEG_F;
        }
    }
}

// ---------------------------------------------------------------------------
// Tail: per-b softmax over S=256 (x2), weighted fact sums, BN + final MLP
// ---------------------------------------------------------------------------
__global__ __launch_bounds__(256) void k_tail(
    const int* __restrict__ mid, const int* __restrict__ click_his,
    const float* __restrict__ click_mask,
    const float* __restrict__ emb, const float* __restrict__ unatt,
    const float* __restrict__ coef,
    const float* __restrict__ scores_c, const float* __restrict__ scores_u,
    const float* __restrict__ bn_g, const float* __restrict__ bn_b,
    const float* __restrict__ bn_m, const float* __restrict__ bn_v,
    const float* __restrict__ fW1, const float* __restrict__ fb1, const float* __restrict__ a1,
    const float* __restrict__ fW2, const float* __restrict__ fb2, const float* __restrict__ a2,
    const float* __restrict__ fW3, const float* __restrict__ fb3,
    float* __restrict__ out)
{
    const int b = blockIdx.x, t = threadIdx.x;
    const int lane = t & 63, wv = t >> 6;

    __shared__ float x[FF];
    __shared__ float sa[SS];
    __shared__ float red[8];
    __shared__ float part[4][DD];
    __shared__ float h1[FH1];
    __shared__ float h2[FH2];

    if (t < DD) x[t] = emb[(size_t)mid[b] * DD + t];

    for (int ty = 0; ty < 2; ++ty) {
        const float sc = (ty ? scores_u : scores_c)[b * SS + t];
        float m = sc;
        #pragma unroll
        for (int o = 32; o > 0; o >>= 1) m = fmaxf(m, __shfl_down(m, o, 64));
        if (lane == 0) red[wv] = m;
        __syncthreads();
        m = fmaxf(fmaxf(red[0], red[1]), fmaxf(red[2], red[3]));
        const float e = __expf(sc - m);
        sa[t] = e;
        float s = e;
        #pragma unroll
        for (int o = 32; o > 0; o >>= 1) s += __shfl_down(s, o, 64);
        if (lane == 0) red[4 + wv] = s;
        __syncthreads();
        const float inv = 1.0f / (red[4] + red[5] + red[6] + red[7]);

        float acc = 0.0f;
        for (int s2 = wv * 64; s2 < wv * 64 + 64; ++s2) {
            const int bs = b * SS + s2;
            const float fvv = ty ? unatt[(size_t)bs * DD + lane]
                                 : emb[(size_t)click_his[bs] * DD + lane] * click_mask[bs] * coef[bs];
            acc += sa[s2] * inv * fvv;
        }
        part[wv][lane] = acc;
        __syncthreads();
        if (t < DD) x[DD + ty * DD + t] = part[0][t] + part[1][t] + part[2][t] + part[3][t];
        __syncthreads();
    }

    if (t < FF) x[t] = (x[t] - bn_m[t]) * rsqrtf(bn_v[t] + 1e-3f) * bn_g[t] + bn_b[t];
    __syncthreads();
    if (t < FH1) {
        float acc = fb1[t];
        #pragma unroll 4
        for (int i = 0; i < FF; ++i) acc += x[i] * fW1[i * FH1 + t];
        h1[t] = fmaxf(acc, 0.0f) + a1[t] * fminf(acc, 0.0f);
    }
    __syncthreads();
    if (t < FH2) {
        float acc = fb2[t];
        #pragma unroll 4
        for (int i = 0; i < FH1; ++i) acc += h1[i] * fW2[i * FH2 + t];
        h2[t] = fmaxf(acc, 0.0f) + a2[t] * fminf(acc, 0.0f);
    }
    __syncthreads();
    if (t == 0) {
        float l0 = fb3[0], l1 = fb3[1];
        for (int i = 0; i < FH2; ++i) {
            l0 += h2[i] * fW3[i * 2 + 0];
            l1 += h2[i] * fW3[i * 2 + 1];
        }
        const float mx = fmaxf(l0, l1);
        const float e0 = __expf(l0 - mx), e1 = __expf(l1 - mx);
        const float inv = 1.0f / (e0 + e1);
        out[b * 2 + 0] = e0 * inv + 1e-8f;
        out[b * 2 + 1] = e1 * inv + 1e-8f;
    }
}

// ---------------------------------------------------------------------------
extern "C" void kernel_launch(void* const* d_in, const int* in_sizes, int n_in,
                              void* d_out, int out_size, void* d_ws, size_t ws_size,
                              hipStream_t stream) {
    const int*   mid          = (const int*)d_in[0];
    const int*   click_his    = (const int*)d_in[1];
    const int*   unclick_his  = (const int*)d_in[2];
    const float* click_mask   = (const float*)d_in[3];
    const float* unclick_mask = (const float*)d_in[4];
    const float* emb          = (const float*)d_in[5];
    const float* sW1 = (const float*)d_in[6];  const float* sb1 = (const float*)d_in[7];
    const float* sW2 = (const float*)d_in[8];  const float* sb2 = (const float*)d_in[9];
    const float* sW3 = (const float*)d_in[10]; const float* sb3 = (const float*)d_in[11];
    const float* cW1 = (const float*)d_in[12]; const float* cb1 = (const float*)d_in[13];
    const float* cW2 = (const float*)d_in[14]; const float* cb2 = (const float*)d_in[15];
    const float* cW3 = (const float*)d_in[16]; const float* cb3 = (const float*)d_in[17];
    const float* uW1 = (const float*)d_in[18]; const float* ub1 = (const float*)d_in[19];
    const float* uW2 = (const float*)d_in[20]; const float* ub2 = (const float*)d_in[21];
    const float* uW3 = (const float*)d_in[22]; const float* ub3 = (const float*)d_in[23];
    const float* bn_g = (const float*)d_in[24]; const float* bn_b = (const float*)d_in[25];
    const float* bn_m = (const float*)d_in[26]; const float* bn_v = (const float*)d_in[27];
    const float* fW1 = (const float*)d_in[28]; const float* fb1 = (const float*)d_in[29];
    const float* a1  = (const float*)d_in[30];
    const float* fW2 = (const float*)d_in[31]; const float* fb2 = (const float*)d_in[32];
    const float* a2  = (const float*)d_in[33];
    const float* fW3 = (const float*)d_in[34]; const float* fb3 = (const float*)d_in[35];

    float* out = (float*)d_out;

    // Workspace layout (bytes, 16B-aligned)
    char* w = (char*)d_ws;
    __bf16* Wt      = (__bf16*)(w + 0);       // 3*41984 = 125952 B
    float* scores_c = (float*)(w + 125952);   // 16384 f32 = 65536 B
    float* scores_u = (float*)(w + 191488);   // 65536 B
    float* coef     = (float*)(w + 257024);   // 65536 B
    float* unatt    = (float*)(w + 322560);   // 16384*64 f32 = 4194304 B

    hipLaunchKernelGGL(k_prep, dim3(3, 10), dim3(256), 0, stream,
        sW1, sW2, cW1, cW2, uW1, uW2, Wt);

    hipLaunchKernelGGL(k_din0, dim3(2048), dim3(320), 0, stream,
        click_his, unclick_his, click_mask, unclick_mask, emb, Wt,
        sb1, sb2, sW3, sb3, unatt, coef);

    hipLaunchKernelGGL(k_din12, dim3(256, 2), dim3(256), 0, stream,
        mid, click_his, click_mask, emb, unatt, coef, Wt,
        cb1, cb2, cW3, cb3, ub1, ub2, uW3, ub3, scores_c, scores_u);

    hipLaunchKernelGGL(k_tail, dim3(BB), dim3(256), 0, stream,
        mid, click_his, click_mask, emb, unatt, coef, scores_c, scores_u,
        bn_g, bn_b, bn_m, bn_v, fW1, fb1, a1, fW2, fb2, a2, fW3, fb3, out);
}